// Round 18
// baseline (349.446 us; speedup 1.0000x reference)
//
#include <hip/hip_runtime.h>
#include <hip/hip_bf16.h>

// ---------------- problem constants (match reference) ----------------
static constexpr int N_NODES = 100000;
static constexpr int N_EDGES = 3200000;
static constexpr int NFEAT   = 512;
static constexpr int NHID    = 256;
static constexpr int NCLASS  = 64;

// bucketed CSR build (r16/r17): 256 nodes per bucket.
static constexpr int BK2_SHIFT = 8;
static constexpr int NBUCK2 = (N_NODES + 255) >> 8;            // 391
static constexpr int BIN_EPB = 8192;                           // 1024 thr * 8
static constexpr int NBIN = (N_EDGES + BIN_EPB - 1) / BIN_EPB; // 391

using short8 = __attribute__((ext_vector_type(8))) short;
using f32x4  = __attribute__((ext_vector_type(4))) float;
using fv4    = __attribute__((ext_vector_type(4))) float;
using fv2    = __attribute__((ext_vector_type(2))) float;
using iv4    = __attribute__((ext_vector_type(4))) int;
using iv2    = __attribute__((ext_vector_type(2))) int;
using fvec4  = __attribute__((ext_vector_type(4))) float;

__device__ __forceinline__ short f2bf_bits(float f) {
    __hip_bfloat16 h = __float2bfloat16(f);
    return *reinterpret_cast<short*>(&h);
}

// fp8 (OCP e4m3) helpers — gfx950 v_cvt_pk_* instructions
__device__ __forceinline__ unsigned char f2fp8(float v) {
    int p = __builtin_amdgcn_cvt_pk_fp8_f32(v, v, 0, false);
    return (unsigned char)(p & 0xff);
}

// acc2[0..3] += w * fp8[0..7] (packed fv2 -> v_pk_fma_f32)
__device__ __forceinline__ void fp8x8_acc_pk(int vx, int vy, float w, fv2* acc2) {
    fv2 w2; w2[0] = w; w2[1] = w;
    acc2[0] += w2 * __builtin_amdgcn_cvt_pk_f32_fp8(vx, false);
    acc2[1] += w2 * __builtin_amdgcn_cvt_pk_f32_fp8(vx, true);
    acc2[2] += w2 * __builtin_amdgcn_cvt_pk_f32_fp8(vy, false);
    acc2[3] += w2 * __builtin_amdgcn_cvt_pk_f32_fp8(vy, true);
}

// acc2[0..7] += w * fp8[0..15] (16 cols from one 16B gather)
__device__ __forceinline__ void fp8x16_acc_pk(iv4 v, float w, fv2* acc2) {
    fp8x8_acc_pk(v.x, v.y, w, acc2);
    fp8x8_acc_pk(v.z, v.w, w, acc2 + 4);
}

#define GLOBAL_TO_LDS(gsrc, ldst)                                                        \
    __builtin_amdgcn_global_load_lds((const __attribute__((address_space(1))) void*)(gsrc), \
                                     (__attribute__((address_space(3))) void*)(ldst), 16, 0, 0)

// ---------------- CSR build (fully bucketed) ----------------
__global__ void zero512_kernel(int* __restrict__ p) { p[threadIdx.x] = 0; }

__global__ __launch_bounds__(1024) void bucket_hist_kernel(const int* __restrict__ edst,
                                                           int* __restrict__ bcnt) {
    __shared__ int lcount[NBUCK2];
    int tid = threadIdx.x;
    if (tid < NBUCK2) lcount[tid] = 0;
    __syncthreads();
    int e0 = blockIdx.x * BIN_EPB + tid * 8;
    if (e0 < N_EDGES) {
        iv4 d0 = __builtin_nontemporal_load((const iv4*)(edst + e0));
        iv4 d1 = __builtin_nontemporal_load((const iv4*)(edst + e0 + 4));
        atomicAdd(&lcount[d0.x >> BK2_SHIFT], 1);
        atomicAdd(&lcount[d0.y >> BK2_SHIFT], 1);
        atomicAdd(&lcount[d0.z >> BK2_SHIFT], 1);
        atomicAdd(&lcount[d0.w >> BK2_SHIFT], 1);
        atomicAdd(&lcount[d1.x >> BK2_SHIFT], 1);
        atomicAdd(&lcount[d1.y >> BK2_SHIFT], 1);
        atomicAdd(&lcount[d1.z >> BK2_SHIFT], 1);
        atomicAdd(&lcount[d1.w >> BK2_SHIFT], 1);
    }
    __syncthreads();
    if (tid < NBUCK2) atomicAdd(&bcnt[tid], lcount[tid]);
}

__global__ __launch_bounds__(512) void bucket_scan_kernel(const int* __restrict__ bcnt,
                                                          int* __restrict__ boffs,
                                                          int* __restrict__ bucket_cursor,
                                                          int* __restrict__ row_ptr) {
    __shared__ int sd[512];
    int t = threadIdx.x;
    int v = (t < NBUCK2) ? bcnt[t] : 0;
    sd[t] = v;
    __syncthreads();
    for (int off = 1; off < 512; off <<= 1) {
        int x = (t >= off) ? sd[t - off] : 0;
        __syncthreads();
        sd[t] += x;
        __syncthreads();
    }
    int excl = sd[t] - v;
    if (t < NBUCK2) { boffs[t] = excl; bucket_cursor[t] = excl; }
    if (t == 0) { boffs[NBUCK2] = N_EDGES; row_ptr[N_NODES] = N_EDGES; }
}

__global__ __launch_bounds__(1024) void bin_kernel(const int* __restrict__ esrc,
                                                   const int* __restrict__ edst,
                                                   const float* __restrict__ ew,
                                                   int* __restrict__ bucket_cursor,
                                                   int2* __restrict__ spk) {
    __shared__ int lcount[NBUCK2];
    __shared__ int lbase[NBUCK2];
    int tid = threadIdx.x;
    if (tid < NBUCK2) lcount[tid] = 0;
    __syncthreads();
    int e0 = blockIdx.x * BIN_EPB + tid * 8;
    bool act = (e0 < N_EDGES);
    int dd[8], ss[8], wb[8], bi[8], rank[8];
    if (act) {
        iv4 d0 = __builtin_nontemporal_load((const iv4*)(edst + e0));
        iv4 d1 = __builtin_nontemporal_load((const iv4*)(edst + e0 + 4));
        iv4 s0 = __builtin_nontemporal_load((const iv4*)(esrc + e0));
        iv4 s1 = __builtin_nontemporal_load((const iv4*)(esrc + e0 + 4));
        iv4 w0 = __builtin_nontemporal_load((const iv4*)(ew + e0));
        iv4 w1 = __builtin_nontemporal_load((const iv4*)(ew + e0 + 4));
        dd[0]=d0.x; dd[1]=d0.y; dd[2]=d0.z; dd[3]=d0.w;
        dd[4]=d1.x; dd[5]=d1.y; dd[6]=d1.z; dd[7]=d1.w;
        ss[0]=s0.x; ss[1]=s0.y; ss[2]=s0.z; ss[3]=s0.w;
        ss[4]=s1.x; ss[5]=s1.y; ss[6]=s1.z; ss[7]=s1.w;
        wb[0]=w0.x; wb[1]=w0.y; wb[2]=w0.z; wb[3]=w0.w;
        wb[4]=w1.x; wb[5]=w1.y; wb[6]=w1.z; wb[7]=w1.w;
#pragma unroll
        for (int k = 0; k < 8; ++k) {
            bi[k] = dd[k] >> BK2_SHIFT;
            rank[k] = atomicAdd(&lcount[bi[k]], 1);
        }
    }
    __syncthreads();
    if (tid < NBUCK2) lbase[tid] = atomicAdd(&bucket_cursor[tid], lcount[tid]);
    __syncthreads();
    if (act) {
#pragma unroll
        for (int k = 0; k < 8; ++k) {
            int pos = lbase[bi[k]] + rank[k];
            int ld = dd[k] & 255;
            spk[pos] = make_int2(ss[k] | (ld << 17), wb[k]);
        }
    }
}

__global__ __launch_bounds__(512) void finalize_bucket_kernel(const int2* __restrict__ spk,
                                                              const int* __restrict__ boffs,
                                                              int* __restrict__ row_ptr,
                                                              int2* __restrict__ pk) {
    int b = blockIdx.x;
    int nb0 = b << BK2_SHIFT;
    int nnode = N_NODES - nb0; if (nnode > 256) nnode = 256;
    int start = boffs[b], end = boffs[b + 1];
    __shared__ int cnt[256];
    __shared__ int pref[256];
    int tid = threadIdx.x;
    if (tid < 256) cnt[tid] = 0;
    __syncthreads();
    for (int e = start + tid; e < end; e += 512) {
        int ld = ((unsigned)spk[e].x >> 17) & 255;
        atomicAdd(&cnt[ld], 1);
    }
    __syncthreads();
    if (tid < 256) pref[tid] = cnt[tid];
    __syncthreads();
    for (int off = 1; off < 256; off <<= 1) {
        int x = 0;
        if (tid < 256 && tid >= off) x = pref[tid - off];
        __syncthreads();
        if (tid < 256) pref[tid] += x;
        __syncthreads();
    }
    if (tid < 256) {
        int excl = pref[tid] - cnt[tid];
        if (tid < nnode) row_ptr[nb0 + tid] = start + excl;
        cnt[tid] = excl;               // reuse as local cursor
    }
    __syncthreads();
    for (int e = start + tid; e < end; e += 512) {
        int2 s = spk[e];
        int ld = ((unsigned)s.x >> 17) & 255;
        int pos = start + atomicAdd(&cnt[ld], 1);
        pk[pos] = make_int2(s.x & 0x1FFFF, s.y);
    }
}

// ---------------- small transpose+cast: W[K][N] f32 -> WT[N][K] bf16 ----------------
__global__ __launch_bounds__(256) void transpose_w_kernel(const float* __restrict__ W,
                                                          __hip_bfloat16* __restrict__ WT,
                                                          int K, int N) {
    int idx = blockIdx.x * 256 + threadIdx.x;
    if (idx < K * N) {
        int k = idx / N, n = idx % N;
        WT[(size_t)n * K + k] = __float2bfloat16(W[idx]);
    }
}

// ---------------- GEMM1: support0[M,256](fp8) = A[M,512](f32) @ W1T[256,512]^T -------
__global__ __launch_bounds__(512) void gemm1_mfma(const float* __restrict__ A,
                                                  const __hip_bfloat16* __restrict__ BT,
                                                  unsigned char* __restrict__ C8,
                                                  int M) {
    constexpr int K = NFEAT;   // 512
    constexpr int N = NHID;    // 256
    constexpr int BM = 128, BK = 32;
    constexpr int NSTEP = K / BK;  // 16
    __shared__ __align__(16) float          As[2][BM * BK];  // 2 x 16 KB
    __shared__ __align__(16) __hip_bfloat16 Bs[2][256 * BK]; // 2 x 16 KB
    const int tid = threadIdx.x;
    const int lane = tid & 63, wave = tid >> 6;   // 8 waves
    const int wr = wave >> 2, wc = wave & 3;      // 2 x 4 wave grid
    const int laneRow = lane & 15, laneK = lane >> 4;
    const int row0 = blockIdx.x * BM;

    f32x4 acc[4][4] = {};

    auto STAGE = [&](int step) {
        {
            float* dst = As[step & 1];
#pragma unroll
            for (int it = 0; it < 2; ++it) {
                int q = wave * 2 + it;            // 16 chunks of 1KB
                int r = q * 8 + (lane >> 3);
                int c16 = lane & 7;
                int src_c = (c16 ^ ((r & 3) << 1)) * 4;  // floats
                int rg = row0 + r; rg = (rg < M) ? rg : (M - 1);
                const float* src = A + (size_t)rg * K + step * BK + src_c;
                GLOBAL_TO_LDS(src, dst + q * 256 + lane * 4);
            }
        }
        {
            __hip_bfloat16* dst = Bs[step & 1];
#pragma unroll
            for (int it = 0; it < 2; ++it) {
                int idx2 = tid + it * 512;        // 1024 granules of 16B
                int n = idx2 >> 2;
                int gk = (idx2 & 3) ^ ((n >> 1) & 3);
                const __hip_bfloat16* src = BT + (size_t)n * K + step * BK + gk * 8;
                GLOBAL_TO_LDS(src, dst + (size_t)idx2 * 8);
            }
        }
    };

    STAGE(0);

#pragma unroll
    for (int t = 0; t < NSTEP; ++t) {
        __syncthreads();
        if (t + 1 < NSTEP) STAGE(t + 1);
        short8 af[4];
#pragma unroll
        for (int i = 0; i < 4; ++i) {
            int rr = wr * 64 + i * 16 + laneRow;
            int ck = laneK ^ (rr & 3);
            const float* ap = As[t & 1] + rr * BK + ck * 8;
            fv4 a0 = *(const fv4*)ap;
            fv4 a1 = *(const fv4*)(ap + 4);
            short8 v;
#pragma unroll
            for (int j = 0; j < 4; ++j) v[j] = f2bf_bits(a0[j]);
#pragma unroll
            for (int j = 0; j < 4; ++j) v[4 + j] = f2bf_bits(a1[j]);
            af[i] = v;
        }
        short8 bfr[4];
#pragma unroll
        for (int j = 0; j < 4; ++j) {
            int n = wc * 64 + j * 16 + laneRow;
            int pg = laneK ^ ((n >> 1) & 3);
            bfr[j] = *(const short8*)(Bs[t & 1] + n * BK + pg * 8);
        }
#pragma unroll
        for (int i = 0; i < 4; ++i)
#pragma unroll
            for (int j = 0; j < 4; ++j)
                acc[i][j] = __builtin_amdgcn_mfma_f32_16x16x32_bf16(af[i], bfr[j], acc[i][j], 0, 0, 0);
    }
#pragma unroll
    for (int i = 0; i < 4; ++i) {
        int rbase = row0 + wr * 64 + i * 16 + laneK * 4;
#pragma unroll
        for (int j = 0; j < 4; ++j) {
            int col = wc * 64 + j * 16 + laneRow;
#pragma unroll
            for (int q = 0; q < 4; ++q) {
                int row = rbase + q;
                if (row < M) C8[(size_t)row * N + col] = f2fp8(acc[i][j][q]);
            }
        }
    }
}

// ---------------- FUSED SPMM1 + GEMM2 ------------------------------------------------
// r18: block = 16 nodes (4 waves x 4 sequential nodes). Phase 1: spmm1 per node
// (4 edge slots x 16 col chunks, 16B fp8 gathers, packed fv2 fma); relu'd H0 row
// written as bf16 into a swizzled LDS tile (chunk p = ck ^ (r&15) -> 2-way-free
// MFMA-fragment reads). Phase 2: each wave MFMAs its 16x16 quadrant of
// support1[16 nodes][64] against LDS-staged W2T. Kills the gemm2 dispatch and the
// entire H0 global round-trip (~102 MB logical).
__global__ __launch_bounds__(256) void spmm1_gemm2_kernel(const unsigned char* __restrict__ s0_8,
                                                          const int* __restrict__ row_ptr,
                                                          const int2* __restrict__ pk,
                                                          const float* __restrict__ b1,
                                                          const __hip_bfloat16* __restrict__ W2T,
                                                          unsigned char* __restrict__ S1) {
    __shared__ __align__(16) __hip_bfloat16 H0s[16 * NHID];   // 8 KB, swizzled
    __shared__ __align__(16) __hip_bfloat16 W2s[NCLASS * NHID]; // 32 KB, swizzled
    const int tid = threadIdx.x;
    const int lane = tid & 63, wave = tid >> 6;
    const int laneRow = lane & 15, laneK = lane >> 4;
    const int nbase = blockIdx.x * 16;

    // stage W2T (async; drained by the barrier after phase 1)
#pragma unroll
    for (int it = 0; it < 8; ++it) {
        int idx = tid + it * 256;
        int n = idx >> 5;
        int kk = (idx & 31) ^ (n & 7);
        const __hip_bfloat16* src = W2T + (size_t)n * NHID + kk * 8;
        GLOBAL_TO_LDS(src, W2s + (size_t)idx * 8);
    }

    // ---- phase 1: spmm1 for this wave's 4 nodes ----
    int j = lane >> 4;                 // edge slot 0..3
    int c = laneRow;                   // column chunk (16 cols each)
    int coff = c * 16;
#pragma unroll
    for (int ln4 = 0; ln4 < 4; ++ln4) {
        int r = wave * 4 + ln4;        // local row 0..15
        int node = nbase + r;
        int beg = row_ptr[node], end = row_ptr[node + 1];
        fv2 acc2[8] = {};
        for (int base = beg; base + j < end; base += 8) {
            int2 pe0 = pk[base + j];
            int i1 = base + 4 + j;
            int2 pe1 = (i1 < end) ? pk[i1] : make_int2(0, 0);
            float w0 = __int_as_float(pe0.y);
            float w1 = __int_as_float(pe1.y);
            iv4 v0 = *(const iv4*)(s0_8 + (size_t)pe0.x * NHID + coff);
            iv4 v1 = *(const iv4*)(s0_8 + (size_t)pe1.x * NHID + coff);
            fp8x16_acc_pk(v0, w0, acc2);
            fp8x16_acc_pk(v1, w1, acc2);
        }
        float accf[16];
#pragma unroll
        for (int k = 0; k < 8; ++k) { accf[2 * k] = acc2[k][0]; accf[2 * k + 1] = acc2[k][1]; }
#pragma unroll
        for (int m = 16; m < 64; m <<= 1)
#pragma unroll
            for (int k = 0; k < 16; ++k) accf[k] += __shfl_xor(accf[k], m);
        if (lane < 16) {
            short8 o0, o1;
#pragma unroll
            for (int k = 0; k < 8; ++k) o0[k] = f2bf_bits(fmaxf(accf[k] + b1[coff + k], 0.f));
#pragma unroll
            for (int k = 0; k < 8; ++k) o1[k] = f2bf_bits(fmaxf(accf[8 + k] + b1[coff + 8 + k], 0.f));
            int p0 = (2 * c) ^ (r & 15);
            int p1 = (2 * c + 1) ^ (r & 15);
            *(short8*)(H0s + r * NHID + p0 * 8) = o0;
            *(short8*)(H0s + r * NHID + p1 * 8) = o1;
        }
    }
    __syncthreads();   // H0s complete + W2s staged (vmcnt drained)

    // ---- phase 2: wave w computes support1[16 nodes][16w .. 16w+16) ----
    f32x4 acc = {};
#pragma unroll
    for (int s = 0; s < 8; ++s) {
        int ckA = (4 * s + laneK) ^ (laneRow & 15);
        short8 af = *(const short8*)(H0s + laneRow * NHID + ckA * 8);
        int n = wave * 16 + laneRow;
        int pkk = (4 * s + laneK) ^ (n & 7);
        short8 bf = *(const short8*)(W2s + n * NHID + pkk * 8);
        acc = __builtin_amdgcn_mfma_f32_16x16x32_bf16(af, bf, acc, 0, 0, 0);
    }
    // C/D: col = lane&15, row = (lane>>4)*4 + q
    int col = wave * 16 + laneRow;
#pragma unroll
    for (int q = 0; q < 4; ++q) {
        int row = laneK * 4 + q;
        S1[(size_t)(nbase + row) * NCLASS + col] = f2fp8(acc[q]);
    }
}

// ---------------- SPMM layer2 + bias + log_softmax ----------------------------------
__global__ __launch_bounds__(256) void spmm2_softmax_kernel(const unsigned char* __restrict__ s1_8,
                                                            const int* __restrict__ row_ptr,
                                                            const int2* __restrict__ pk,
                                                            const float* __restrict__ b2,
                                                            float* __restrict__ out) {
    int node = blockIdx.x * 4 + (threadIdx.x >> 6);
    int lane = threadIdx.x & 63;
    int j = lane >> 3;   // edge slot 0..7
    int c = lane & 7;    // class chunk (8 classes each)
    int beg = row_ptr[node], end = row_ptr[node + 1];
    fv2 acc2[4] = {};
    for (int base = beg; base + j < end; base += 16) {
        int2 pe0 = pk[base + j];
        int i1 = base + 8 + j;
        int2 pe1 = (i1 < end) ? pk[i1] : make_int2(0, 0);
        float w0 = __int_as_float(pe0.y);
        float w1 = __int_as_float(pe1.y);
        int2 v0 = *(const int2*)(s1_8 + (size_t)pe0.x * NCLASS + c * 8);
        int2 v1 = *(const int2*)(s1_8 + (size_t)pe1.x * NCLASS + c * 8);
        fp8x8_acc_pk(v0.x, v0.y, w0, acc2);
        fp8x8_acc_pk(v1.x, v1.y, w1, acc2);
    }
    float acc[8];
#pragma unroll
    for (int k = 0; k < 4; ++k) { acc[2 * k] = acc2[k][0]; acc[2 * k + 1] = acc2[k][1]; }
#pragma unroll
    for (int m = 8; m < 64; m <<= 1)
#pragma unroll
        for (int k = 0; k < 8; ++k) acc[k] += __shfl_xor(acc[k], m);

    fv4 blo = *(const fv4*)(b2 + c * 8);
    fv4 bhi = *(const fv4*)(b2 + c * 8 + 4);
    float z[8];
#pragma unroll
    for (int k = 0; k < 4; ++k) z[k] = acc[k] + blo[k];
#pragma unroll
    for (int k = 0; k < 4; ++k) z[4 + k] = acc[4 + k] + bhi[k];

    float mx = z[0];
#pragma unroll
    for (int k = 1; k < 8; ++k) mx = fmaxf(mx, z[k]);
#pragma unroll
    for (int m = 1; m < 8; m <<= 1) mx = fmaxf(mx, __shfl_xor(mx, m));
    float s = 0.f;
#pragma unroll
    for (int k = 0; k < 8; ++k) s += __expf(z[k] - mx);
#pragma unroll
    for (int m = 1; m < 8; m <<= 1) s += __shfl_xor(s, m);
    float lg = __logf(s);
    if (lane < 8) {
        f32x4 o0, o1;
#pragma unroll
        for (int k = 0; k < 4; ++k) o0[k] = z[k] - mx - lg;
#pragma unroll
        for (int k = 0; k < 4; ++k) o1[k] = z[4 + k] - mx - lg;
        float* dst = out + (size_t)node * NCLASS + c * 8;
        *(f32x4*)dst = o0;
        *(f32x4*)(dst + 4) = o1;
    }
}

// ---------------- host launch ----------------
extern "C" void kernel_launch(void* const* d_in, const int* in_sizes, int n_in,
                              void* d_out, int out_size, void* d_ws, size_t ws_size,
                              hipStream_t stream) {
    const float* x    = (const float*)d_in[0];
    const int*   esrc = (const int*)d_in[1];
    const int*   edst = (const int*)d_in[2];
    const float* ew   = (const float*)d_in[3];
    const float* W1   = (const float*)d_in[4];
    const float* b1   = (const float*)d_in[5];
    const float* W2   = (const float*)d_in[6];
    const float* b2   = (const float*)d_in[7];
    float* out = (float*)d_out;

    char* ws = (char*)d_ws;
    size_t off = 0;
    auto alloc = [&](size_t bytes) {
        size_t o = off;
        off = (off + bytes + 255) & ~(size_t)255;
        return o;
    };
    unsigned char* support0 = (unsigned char*)(ws + alloc((size_t)N_NODES * NHID));
    unsigned char* support1 = (unsigned char*)(ws + alloc((size_t)N_NODES * NCLASS));
    int2*  pk         = (int2*)(ws + alloc((size_t)N_EDGES * 8));
    int2*  spk        = (int2*)(ws + alloc((size_t)N_EDGES * 8));
    int*   row_ptr    = (int*)(ws + alloc((size_t)(N_NODES + 1) * 4));
    int*   bcnt       = (int*)(ws + alloc(512 * 4));
    int*   boffs      = (int*)(ws + alloc(512 * 4));
    int*   bucket_cursor = (int*)(ws + alloc(512 * 4));
    __hip_bfloat16* W1T = (__hip_bfloat16*)(ws + alloc((size_t)NHID * NFEAT * 2));
    __hip_bfloat16* W2T = (__hip_bfloat16*)(ws + alloc((size_t)NCLASS * NHID * 2));

    // --- weight transposes (bf16) ---
    transpose_w_kernel<<<(NFEAT * NHID + 255) / 256, 256, 0, stream>>>(W1, W1T, NFEAT, NHID);
    transpose_w_kernel<<<(NHID * NCLASS + 255) / 256, 256, 0, stream>>>(W2, W2T, NHID, NCLASS);

    // --- bucketed CSR build ---
    zero512_kernel<<<1, 512, 0, stream>>>(bcnt);
    bucket_hist_kernel<<<NBIN, 1024, 0, stream>>>(edst, bcnt);
    bucket_scan_kernel<<<1, 512, 0, stream>>>(bcnt, boffs, bucket_cursor, row_ptr);
    bin_kernel<<<NBIN, 1024, 0, stream>>>(esrc, edst, ew, bucket_cursor, spk);
    finalize_bucket_kernel<<<NBUCK2, 512, 0, stream>>>(spk, boffs, row_ptr, pk);

    // --- Layer 1 GEMM ---
    gemm1_mfma<<<(N_NODES + 127) / 128, 512, 0, stream>>>(x, W1T, support0, N_NODES);

    // --- FUSED spmm1 + gemm2 ---
    spmm1_gemm2_kernel<<<N_NODES / 16, 256, 0, stream>>>(support0, row_ptr, pk, b1, W2T,
                                                         support1);

    // --- Layer 2 aggregate + log_softmax ---
    spmm2_softmax_kernel<<<N_NODES / 4, 256, 0, stream>>>(support1, row_ptr, pk, b2, out);
}

// Round 19
// 331.750 us; speedup vs baseline: 1.0533x; 1.0533x over previous
//
#include <hip/hip_runtime.h>
#include <hip/hip_bf16.h>

// ---------------- problem constants (match reference) ----------------
static constexpr int N_NODES = 100000;
static constexpr int N_EDGES = 3200000;
static constexpr int NFEAT   = 512;
static constexpr int NHID    = 256;
static constexpr int NCLASS  = 64;

// bucketed CSR build (r16/r17): 256 nodes per bucket.
static constexpr int BK2_SHIFT = 8;
static constexpr int NBUCK2 = (N_NODES + 255) >> 8;            // 391
static constexpr int BIN_EPB = 8192;                           // 1024 thr * 8
static constexpr int NBIN = (N_EDGES + BIN_EPB - 1) / BIN_EPB; // 391

using short8 = __attribute__((ext_vector_type(8))) short;
using f32x4  = __attribute__((ext_vector_type(4))) float;
using fv4    = __attribute__((ext_vector_type(4))) float;
using fv2    = __attribute__((ext_vector_type(2))) float;
using iv4    = __attribute__((ext_vector_type(4))) int;
using iv2    = __attribute__((ext_vector_type(2))) int;
using fvec4  = __attribute__((ext_vector_type(4))) float;

__device__ __forceinline__ short f2bf_bits(float f) {
    __hip_bfloat16 h = __float2bfloat16(f);
    return *reinterpret_cast<short*>(&h);
}

// fp8 (OCP e4m3) helpers — gfx950 v_cvt_pk_* instructions
__device__ __forceinline__ unsigned char f2fp8(float v) {
    int p = __builtin_amdgcn_cvt_pk_fp8_f32(v, v, 0, false);
    return (unsigned char)(p & 0xff);
}

// acc2[0..3] += w * fp8[0..7] (packed fv2 -> v_pk_fma_f32)
__device__ __forceinline__ void fp8x8_acc_pk(int vx, int vy, float w, fv2* acc2) {
    fv2 w2; w2[0] = w; w2[1] = w;
    acc2[0] += w2 * __builtin_amdgcn_cvt_pk_f32_fp8(vx, false);
    acc2[1] += w2 * __builtin_amdgcn_cvt_pk_f32_fp8(vx, true);
    acc2[2] += w2 * __builtin_amdgcn_cvt_pk_f32_fp8(vy, false);
    acc2[3] += w2 * __builtin_amdgcn_cvt_pk_f32_fp8(vy, true);
}

// acc2[0..7] += w * fp8[0..15] (16 cols from one 16B gather)
__device__ __forceinline__ void fp8x16_acc_pk(iv4 v, float w, fv2* acc2) {
    fp8x8_acc_pk(v.x, v.y, w, acc2);
    fp8x8_acc_pk(v.z, v.w, w, acc2 + 4);
}

#define GLOBAL_TO_LDS(gsrc, ldst)                                                        \
    __builtin_amdgcn_global_load_lds((const __attribute__((address_space(1))) void*)(gsrc), \
                                     (__attribute__((address_space(3))) void*)(ldst), 16, 0, 0)

// ---------------- CSR build (fully bucketed) ----------------
__global__ void zero512_kernel(int* __restrict__ p) { p[threadIdx.x] = 0; }

__global__ __launch_bounds__(1024) void bucket_hist_kernel(const int* __restrict__ edst,
                                                           int* __restrict__ bcnt) {
    __shared__ int lcount[NBUCK2];
    int tid = threadIdx.x;
    if (tid < NBUCK2) lcount[tid] = 0;
    __syncthreads();
    int e0 = blockIdx.x * BIN_EPB + tid * 8;
    if (e0 < N_EDGES) {
        iv4 d0 = __builtin_nontemporal_load((const iv4*)(edst + e0));
        iv4 d1 = __builtin_nontemporal_load((const iv4*)(edst + e0 + 4));
        atomicAdd(&lcount[d0.x >> BK2_SHIFT], 1);
        atomicAdd(&lcount[d0.y >> BK2_SHIFT], 1);
        atomicAdd(&lcount[d0.z >> BK2_SHIFT], 1);
        atomicAdd(&lcount[d0.w >> BK2_SHIFT], 1);
        atomicAdd(&lcount[d1.x >> BK2_SHIFT], 1);
        atomicAdd(&lcount[d1.y >> BK2_SHIFT], 1);
        atomicAdd(&lcount[d1.z >> BK2_SHIFT], 1);
        atomicAdd(&lcount[d1.w >> BK2_SHIFT], 1);
    }
    __syncthreads();
    if (tid < NBUCK2) atomicAdd(&bcnt[tid], lcount[tid]);
}

__global__ __launch_bounds__(512) void bucket_scan_kernel(const int* __restrict__ bcnt,
                                                          int* __restrict__ boffs,
                                                          int* __restrict__ bucket_cursor,
                                                          int* __restrict__ row_ptr) {
    __shared__ int sd[512];
    int t = threadIdx.x;
    int v = (t < NBUCK2) ? bcnt[t] : 0;
    sd[t] = v;
    __syncthreads();
    for (int off = 1; off < 512; off <<= 1) {
        int x = (t >= off) ? sd[t - off] : 0;
        __syncthreads();
        sd[t] += x;
        __syncthreads();
    }
    int excl = sd[t] - v;
    if (t < NBUCK2) { boffs[t] = excl; bucket_cursor[t] = excl; }
    if (t == 0) { boffs[NBUCK2] = N_EDGES; row_ptr[N_NODES] = N_EDGES; }
}

__global__ __launch_bounds__(1024) void bin_kernel(const int* __restrict__ esrc,
                                                   const int* __restrict__ edst,
                                                   const float* __restrict__ ew,
                                                   int* __restrict__ bucket_cursor,
                                                   int2* __restrict__ spk) {
    __shared__ int lcount[NBUCK2];
    __shared__ int lbase[NBUCK2];
    int tid = threadIdx.x;
    if (tid < NBUCK2) lcount[tid] = 0;
    __syncthreads();
    int e0 = blockIdx.x * BIN_EPB + tid * 8;
    bool act = (e0 < N_EDGES);
    int dd[8], ss[8], wb[8], bi[8], rank[8];
    if (act) {
        iv4 d0 = __builtin_nontemporal_load((const iv4*)(edst + e0));
        iv4 d1 = __builtin_nontemporal_load((const iv4*)(edst + e0 + 4));
        iv4 s0 = __builtin_nontemporal_load((const iv4*)(esrc + e0));
        iv4 s1 = __builtin_nontemporal_load((const iv4*)(esrc + e0 + 4));
        iv4 w0 = __builtin_nontemporal_load((const iv4*)(ew + e0));
        iv4 w1 = __builtin_nontemporal_load((const iv4*)(ew + e0 + 4));
        dd[0]=d0.x; dd[1]=d0.y; dd[2]=d0.z; dd[3]=d0.w;
        dd[4]=d1.x; dd[5]=d1.y; dd[6]=d1.z; dd[7]=d1.w;
        ss[0]=s0.x; ss[1]=s0.y; ss[2]=s0.z; ss[3]=s0.w;
        ss[4]=s1.x; ss[5]=s1.y; ss[6]=s1.z; ss[7]=s1.w;
        wb[0]=w0.x; wb[1]=w0.y; wb[2]=w0.z; wb[3]=w0.w;
        wb[4]=w1.x; wb[5]=w1.y; wb[6]=w1.z; wb[7]=w1.w;
#pragma unroll
        for (int k = 0; k < 8; ++k) {
            bi[k] = dd[k] >> BK2_SHIFT;
            rank[k] = atomicAdd(&lcount[bi[k]], 1);
        }
    }
    __syncthreads();
    if (tid < NBUCK2) lbase[tid] = atomicAdd(&bucket_cursor[tid], lcount[tid]);
    __syncthreads();
    if (act) {
#pragma unroll
        for (int k = 0; k < 8; ++k) {
            int pos = lbase[bi[k]] + rank[k];
            int ld = dd[k] & 255;
            spk[pos] = make_int2(ss[k] | (ld << 17), wb[k]);
        }
    }
}

__global__ __launch_bounds__(512) void finalize_bucket_kernel(const int2* __restrict__ spk,
                                                              const int* __restrict__ boffs,
                                                              int* __restrict__ row_ptr,
                                                              int2* __restrict__ pk) {
    int b = blockIdx.x;
    int nb0 = b << BK2_SHIFT;
    int nnode = N_NODES - nb0; if (nnode > 256) nnode = 256;
    int start = boffs[b], end = boffs[b + 1];
    __shared__ int cnt[256];
    __shared__ int pref[256];
    int tid = threadIdx.x;
    if (tid < 256) cnt[tid] = 0;
    __syncthreads();
    for (int e = start + tid; e < end; e += 512) {
        int ld = ((unsigned)spk[e].x >> 17) & 255;
        atomicAdd(&cnt[ld], 1);
    }
    __syncthreads();
    if (tid < 256) pref[tid] = cnt[tid];
    __syncthreads();
    for (int off = 1; off < 256; off <<= 1) {
        int x = 0;
        if (tid < 256 && tid >= off) x = pref[tid - off];
        __syncthreads();
        if (tid < 256) pref[tid] += x;
        __syncthreads();
    }
    if (tid < 256) {
        int excl = pref[tid] - cnt[tid];
        if (tid < nnode) row_ptr[nb0 + tid] = start + excl;
        cnt[tid] = excl;               // reuse as local cursor
    }
    __syncthreads();
    for (int e = start + tid; e < end; e += 512) {
        int2 s = spk[e];
        int ld = ((unsigned)s.x >> 17) & 255;
        int pos = start + atomicAdd(&cnt[ld], 1);
        pk[pos] = make_int2(s.x & 0x1FFFF, s.y);
    }
}

// ---------------- small transpose+cast: W[K][N] f32 -> WT[N][K] bf16 ----------------
__global__ __launch_bounds__(256) void transpose_w_kernel(const float* __restrict__ W,
                                                          __hip_bfloat16* __restrict__ WT,
                                                          int K, int N) {
    int idx = blockIdx.x * 256 + threadIdx.x;
    if (idx < K * N) {
        int k = idx / N, n = idx % N;
        WT[(size_t)n * K + k] = __float2bfloat16(W[idx]);
    }
}

// ---------------- GEMM1: support0[M,256](fp8) = A[M,512](f32) @ W1T[256,512]^T -------
__global__ __launch_bounds__(512) void gemm1_mfma(const float* __restrict__ A,
                                                  const __hip_bfloat16* __restrict__ BT,
                                                  unsigned char* __restrict__ C8,
                                                  int M) {
    constexpr int K = NFEAT;   // 512
    constexpr int N = NHID;    // 256
    constexpr int BM = 128, BK = 32;
    constexpr int NSTEP = K / BK;  // 16
    __shared__ __align__(16) float          As[2][BM * BK];  // 2 x 16 KB
    __shared__ __align__(16) __hip_bfloat16 Bs[2][256 * BK]; // 2 x 16 KB
    const int tid = threadIdx.x;
    const int lane = tid & 63, wave = tid >> 6;   // 8 waves
    const int wr = wave >> 2, wc = wave & 3;      // 2 x 4 wave grid
    const int laneRow = lane & 15, laneK = lane >> 4;
    const int row0 = blockIdx.x * BM;

    f32x4 acc[4][4] = {};

    auto STAGE = [&](int step) {
        {
            float* dst = As[step & 1];
#pragma unroll
            for (int it = 0; it < 2; ++it) {
                int q = wave * 2 + it;            // 16 chunks of 1KB
                int r = q * 8 + (lane >> 3);
                int c16 = lane & 7;
                int src_c = (c16 ^ ((r & 3) << 1)) * 4;  // floats
                int rg = row0 + r; rg = (rg < M) ? rg : (M - 1);
                const float* src = A + (size_t)rg * K + step * BK + src_c;
                GLOBAL_TO_LDS(src, dst + q * 256 + lane * 4);
            }
        }
        {
            __hip_bfloat16* dst = Bs[step & 1];
#pragma unroll
            for (int it = 0; it < 2; ++it) {
                int idx2 = tid + it * 512;        // 1024 granules of 16B
                int n = idx2 >> 2;
                int gk = (idx2 & 3) ^ ((n >> 1) & 3);
                const __hip_bfloat16* src = BT + (size_t)n * K + step * BK + gk * 8;
                GLOBAL_TO_LDS(src, dst + (size_t)idx2 * 8);
            }
        }
    };

    STAGE(0);

#pragma unroll
    for (int t = 0; t < NSTEP; ++t) {
        __syncthreads();
        if (t + 1 < NSTEP) STAGE(t + 1);
        short8 af[4];
#pragma unroll
        for (int i = 0; i < 4; ++i) {
            int rr = wr * 64 + i * 16 + laneRow;
            int ck = laneK ^ (rr & 3);
            const float* ap = As[t & 1] + rr * BK + ck * 8;
            fv4 a0 = *(const fv4*)ap;
            fv4 a1 = *(const fv4*)(ap + 4);
            short8 v;
#pragma unroll
            for (int j = 0; j < 4; ++j) v[j] = f2bf_bits(a0[j]);
#pragma unroll
            for (int j = 0; j < 4; ++j) v[4 + j] = f2bf_bits(a1[j]);
            af[i] = v;
        }
        short8 bfr[4];
#pragma unroll
        for (int j = 0; j < 4; ++j) {
            int n = wc * 64 + j * 16 + laneRow;
            int pg = laneK ^ ((n >> 1) & 3);
            bfr[j] = *(const short8*)(Bs[t & 1] + n * BK + pg * 8);
        }
#pragma unroll
        for (int i = 0; i < 4; ++i)
#pragma unroll
            for (int j = 0; j < 4; ++j)
                acc[i][j] = __builtin_amdgcn_mfma_f32_16x16x32_bf16(af[i], bfr[j], acc[i][j], 0, 0, 0);
    }
#pragma unroll
    for (int i = 0; i < 4; ++i) {
        int rbase = row0 + wr * 64 + i * 16 + laneK * 4;
#pragma unroll
        for (int j = 0; j < 4; ++j) {
            int col = wc * 64 + j * 16 + laneRow;
#pragma unroll
            for (int q = 0; q < 4; ++q) {
                int row = rbase + q;
                if (row < M) C8[(size_t)row * N + col] = f2fp8(acc[i][j][q]);
            }
        }
    }
}

// ---------------- FUSED SPMM1 + GEMM2 (r19: no W2s LDS staging) ----------------------
// r18 post-mortem: 32KB W2s staging capped occupancy at 40% -> 160us. W2T is 32KB
// total and L2-resident across all 6250 blocks -> phase 2 reads B-fragments straight
// from global. LDS = 8KB (H0s only) -> occupancy back to the wave limit.
__global__ __launch_bounds__(256) void spmm1_gemm2_kernel(const unsigned char* __restrict__ s0_8,
                                                          const int* __restrict__ row_ptr,
                                                          const int2* __restrict__ pk,
                                                          const float* __restrict__ b1,
                                                          const __hip_bfloat16* __restrict__ W2T,
                                                          unsigned char* __restrict__ S1) {
    __shared__ __align__(16) __hip_bfloat16 H0s[16 * NHID];   // 8 KB, swizzled
    const int tid = threadIdx.x;
    const int lane = tid & 63, wave = tid >> 6;
    const int laneRow = lane & 15, laneK = lane >> 4;
    const int nbase = blockIdx.x * 16;

    // ---- phase 1: spmm1 for this wave's 4 nodes ----
    int j = lane >> 4;                 // edge slot 0..3
    int c = laneRow;                   // column chunk (16 cols each)
    int coff = c * 16;
#pragma unroll
    for (int ln4 = 0; ln4 < 4; ++ln4) {
        int r = wave * 4 + ln4;        // local row 0..15
        int node = nbase + r;
        int beg = row_ptr[node], end = row_ptr[node + 1];
        fv2 acc2[8] = {};
        for (int base = beg; base + j < end; base += 8) {
            int2 pe0 = pk[base + j];
            int i1 = base + 4 + j;
            int2 pe1 = (i1 < end) ? pk[i1] : make_int2(0, 0);
            float w0 = __int_as_float(pe0.y);
            float w1 = __int_as_float(pe1.y);
            iv4 v0 = *(const iv4*)(s0_8 + (size_t)pe0.x * NHID + coff);
            iv4 v1 = *(const iv4*)(s0_8 + (size_t)pe1.x * NHID + coff);
            fp8x16_acc_pk(v0, w0, acc2);
            fp8x16_acc_pk(v1, w1, acc2);
        }
        float accf[16];
#pragma unroll
        for (int k = 0; k < 8; ++k) { accf[2 * k] = acc2[k][0]; accf[2 * k + 1] = acc2[k][1]; }
#pragma unroll
        for (int m = 16; m < 64; m <<= 1)
#pragma unroll
            for (int k = 0; k < 16; ++k) accf[k] += __shfl_xor(accf[k], m);
        if (lane < 16) {
            short8 o0, o1;
#pragma unroll
            for (int k = 0; k < 8; ++k) o0[k] = f2bf_bits(fmaxf(accf[k] + b1[coff + k], 0.f));
#pragma unroll
            for (int k = 0; k < 8; ++k) o1[k] = f2bf_bits(fmaxf(accf[8 + k] + b1[coff + 8 + k], 0.f));
            int p0 = (2 * c) ^ (r & 15);
            int p1 = (2 * c + 1) ^ (r & 15);
            *(short8*)(H0s + r * NHID + p0 * 8) = o0;
            *(short8*)(H0s + r * NHID + p1 * 8) = o1;
        }
    }
    __syncthreads();   // H0s complete

    // ---- phase 2: wave w computes support1[16 nodes][16w .. 16w+16) ----
    // B fragments read straight from global W2T (32KB, L2-resident).
    f32x4 acc = {};
    const __hip_bfloat16* w2row = W2T + (size_t)(wave * 16 + laneRow) * NHID + laneK * 8;
#pragma unroll
    for (int s = 0; s < 8; ++s) {
        int ckA = (4 * s + laneK) ^ (laneRow & 15);
        short8 af = *(const short8*)(H0s + laneRow * NHID + ckA * 8);
        short8 bf = *(const short8*)(w2row + s * 32);
        acc = __builtin_amdgcn_mfma_f32_16x16x32_bf16(af, bf, acc, 0, 0, 0);
    }
    // C/D: col = lane&15, row = (lane>>4)*4 + q
    int col = wave * 16 + laneRow;
#pragma unroll
    for (int q = 0; q < 4; ++q) {
        int row = laneK * 4 + q;
        S1[(size_t)(nbase + row) * NCLASS + col] = f2fp8(acc[q]);
    }
}

// ---------------- SPMM layer2 + bias + log_softmax ----------------------------------
__global__ __launch_bounds__(256) void spmm2_softmax_kernel(const unsigned char* __restrict__ s1_8,
                                                            const int* __restrict__ row_ptr,
                                                            const int2* __restrict__ pk,
                                                            const float* __restrict__ b2,
                                                            float* __restrict__ out) {
    int node = blockIdx.x * 4 + (threadIdx.x >> 6);
    int lane = threadIdx.x & 63;
    int j = lane >> 3;   // edge slot 0..7
    int c = lane & 7;    // class chunk (8 classes each)
    int beg = row_ptr[node], end = row_ptr[node + 1];
    fv2 acc2[4] = {};
    for (int base = beg; base + j < end; base += 16) {
        int2 pe0 = pk[base + j];
        int i1 = base + 8 + j;
        int2 pe1 = (i1 < end) ? pk[i1] : make_int2(0, 0);
        float w0 = __int_as_float(pe0.y);
        float w1 = __int_as_float(pe1.y);
        int2 v0 = *(const int2*)(s1_8 + (size_t)pe0.x * NCLASS + c * 8);
        int2 v1 = *(const int2*)(s1_8 + (size_t)pe1.x * NCLASS + c * 8);
        fp8x8_acc_pk(v0.x, v0.y, w0, acc2);
        fp8x8_acc_pk(v1.x, v1.y, w1, acc2);
    }
    float acc[8];
#pragma unroll
    for (int k = 0; k < 4; ++k) { acc[2 * k] = acc2[k][0]; acc[2 * k + 1] = acc2[k][1]; }
#pragma unroll
    for (int m = 8; m < 64; m <<= 1)
#pragma unroll
        for (int k = 0; k < 8; ++k) acc[k] += __shfl_xor(acc[k], m);

    fv4 blo = *(const fv4*)(b2 + c * 8);
    fv4 bhi = *(const fv4*)(b2 + c * 8 + 4);
    float z[8];
#pragma unroll
    for (int k = 0; k < 4; ++k) z[k] = acc[k] + blo[k];
#pragma unroll
    for (int k = 0; k < 4; ++k) z[4 + k] = acc[4 + k] + bhi[k];

    float mx = z[0];
#pragma unroll
    for (int k = 1; k < 8; ++k) mx = fmaxf(mx, z[k]);
#pragma unroll
    for (int m = 1; m < 8; m <<= 1) mx = fmaxf(mx, __shfl_xor(mx, m));
    float s = 0.f;
#pragma unroll
    for (int k = 0; k < 8; ++k) s += __expf(z[k] - mx);
#pragma unroll
    for (int m = 1; m < 8; m <<= 1) s += __shfl_xor(s, m);
    float lg = __logf(s);
    if (lane < 8) {
        f32x4 o0, o1;
#pragma unroll
        for (int k = 0; k < 4; ++k) o0[k] = z[k] - mx - lg;
#pragma unroll
        for (int k = 0; k < 4; ++k) o1[k] = z[4 + k] - mx - lg;
        float* dst = out + (size_t)node * NCLASS + c * 8;
        *(f32x4*)dst = o0;
        *(f32x4*)(dst + 4) = o1;
    }
}

// ---------------- host launch ----------------
extern "C" void kernel_launch(void* const* d_in, const int* in_sizes, int n_in,
                              void* d_out, int out_size, void* d_ws, size_t ws_size,
                              hipStream_t stream) {
    const float* x    = (const float*)d_in[0];
    const int*   esrc = (const int*)d_in[1];
    const int*   edst = (const int*)d_in[2];
    const float* ew   = (const float*)d_in[3];
    const float* W1   = (const float*)d_in[4];
    const float* b1   = (const float*)d_in[5];
    const float* W2   = (const float*)d_in[6];
    const float* b2   = (const float*)d_in[7];
    float* out = (float*)d_out;

    char* ws = (char*)d_ws;
    size_t off = 0;
    auto alloc = [&](size_t bytes) {
        size_t o = off;
        off = (off + bytes + 255) & ~(size_t)255;
        return o;
    };
    unsigned char* support0 = (unsigned char*)(ws + alloc((size_t)N_NODES * NHID));
    unsigned char* support1 = (unsigned char*)(ws + alloc((size_t)N_NODES * NCLASS));
    int2*  pk         = (int2*)(ws + alloc((size_t)N_EDGES * 8));
    int2*  spk        = (int2*)(ws + alloc((size_t)N_EDGES * 8));
    int*   row_ptr    = (int*)(ws + alloc((size_t)(N_NODES + 1) * 4));
    int*   bcnt       = (int*)(ws + alloc(512 * 4));
    int*   boffs      = (int*)(ws + alloc(512 * 4));
    int*   bucket_cursor = (int*)(ws + alloc(512 * 4));
    __hip_bfloat16* W1T = (__hip_bfloat16*)(ws + alloc((size_t)NHID * NFEAT * 2));
    __hip_bfloat16* W2T = (__hip_bfloat16*)(ws + alloc((size_t)NCLASS * NHID * 2));

    // --- weight transposes (bf16) ---
    transpose_w_kernel<<<(NFEAT * NHID + 255) / 256, 256, 0, stream>>>(W1, W1T, NFEAT, NHID);
    transpose_w_kernel<<<(NHID * NCLASS + 255) / 256, 256, 0, stream>>>(W2, W2T, NHID, NCLASS);

    // --- bucketed CSR build ---
    zero512_kernel<<<1, 512, 0, stream>>>(bcnt);
    bucket_hist_kernel<<<NBIN, 1024, 0, stream>>>(edst, bcnt);
    bucket_scan_kernel<<<1, 512, 0, stream>>>(bcnt, boffs, bucket_cursor, row_ptr);
    bin_kernel<<<NBIN, 1024, 0, stream>>>(esrc, edst, ew, bucket_cursor, spk);
    finalize_bucket_kernel<<<NBUCK2, 512, 0, stream>>>(spk, boffs, row_ptr, pk);

    // --- Layer 1 GEMM ---
    gemm1_mfma<<<(N_NODES + 127) / 128, 512, 0, stream>>>(x, W1T, support0, N_NODES);

    // --- FUSED spmm1 + gemm2 ---
    spmm1_gemm2_kernel<<<N_NODES / 16, 256, 0, stream>>>(support0, row_ptr, pk, b1, W2T,
                                                         support1);

    // --- Layer 2 aggregate + log_softmax ---
    spmm2_softmax_kernel<<<N_NODES / 4, 256, 0, stream>>>(support1, row_ptr, pk, b2, out);
}